// Round 1
// baseline (150.013 us; speedup 1.0000x reference)
//
#include <hip/hip_runtime.h>

#define NFULL 128
#define NOUT  122

// s1: [5 quantities][22 rows][32 cols + 4 pad] -> q-stride 792, r-stride 36
// s2: [5 quantities][16 rows][32 cols + 4 pad] -> q-stride 584, r-stride 36

__device__ __forceinline__ void phaseA_task(const float* __restrict__ px,
                                            const float* __restrict__ py,
                                            float* __restrict__ s1p)
{
    float xs[8], ys[8];
#pragma unroll
    for (int k = 0; k < 4; ++k) {
        float2 tx = *(const float2*)(px + 2 * k);
        float2 ty = *(const float2*)(py + 2 * k);
        xs[2 * k] = tx.x; xs[2 * k + 1] = tx.y;
        ys[2 * k] = ty.x; ys[2 * k + 1] = ty.y;
    }
    float sx = 0.f, sy = 0.f, sxx = 0.f, syy = 0.f, sxy = 0.f;
#pragma unroll
    for (int k = 0; k < 7; ++k) {
        sx += xs[k]; sy += ys[k];
        sxx = fmaf(xs[k], xs[k], sxx);
        syy = fmaf(ys[k], ys[k], syy);
        sxy = fmaf(xs[k], ys[k], sxy);
    }
    // second output of the pair: shift window by one
    float tx2 = sx - xs[0] + xs[7];
    float ty2 = sy - ys[0] + ys[7];
    float txx = sxx - xs[0] * xs[0] + xs[7] * xs[7];
    float tyy = syy - ys[0] * ys[0] + ys[7] * ys[7];
    float txy = sxy - xs[0] * ys[0] + xs[7] * ys[7];
    *(float2*)(s1p + 0 * 792) = make_float2(sx,  tx2);
    *(float2*)(s1p + 1 * 792) = make_float2(sy,  ty2);
    *(float2*)(s1p + 2 * 792) = make_float2(sxx, txx);
    *(float2*)(s1p + 3 * 792) = make_float2(syy, tyy);
    *(float2*)(s1p + 4 * 792) = make_float2(sxy, txy);
}

__global__ __launch_bounds__(256, 2)
void ssim3d_kernel(const float* __restrict__ X, const float* __restrict__ Y,
                   const float* __restrict__ DR, double* __restrict__ ws)
{
    __shared__ __align__(16) float s1[5 * 792];
    __shared__ __align__(16) float s2[5 * 584];

    const int tid = threadIdx.x;
    int bi = blockIdx.x;
    const int bb = bi & 3;  bi >>= 2;   // batch
    const int ht = bi & 7;  bi >>= 3;   // 8 h-tiles of 16
    const int wt = bi & 3;  bi >>= 2;   // 4 w-tiles of 32 (last overlaps: w0=90)
    const int dc = bi;                  // 4 d-chunks of 31 outputs

    const int h0 = ht << 4;
    const int w0 = (wt == 3) ? 90 : (wt << 5);
    const int w_hi = (wt == 3) ? 122 : ((wt == 2) ? 90 : (w0 + 32)); // ownership
    const int d0 = dc * 31;
    const int dlast = (d0 + 36 < NFULL) ? (d0 + 36) : (NFULL - 1);
    const int nslices = dlast - d0 + 1;

    const float dr = DR[bb];
    const float c1 = (0.01f * dr) * (0.01f * dr);
    const float c2 = (0.03f * dr) * (0.03f * dr);
    const float inv_n = 1.0f / 343.0f;
    const float covn = 343.0f / 342.0f;

    const int sA  = tid & 15;
    const int rA0 = tid >> 4;
    const int rA1 = 16 + (tid >> 4);    // only for tid < 96

    const int sB = tid & 15, qB = tid >> 4;  // only for tid < 80

    const int sC = tid & 15, hC = tid >> 4;
    const int gh  = h0 + hC;
    const int gw0 = w0 + 2 * sC;
    const bool vh = (gh < NOUT);
    const bool vld0 = vh && (gw0 < w_hi);
    const bool vld1 = vh && (gw0 + 1 < w_hi);

    const size_t planeStride = (size_t)NFULL * NFULL;
    const size_t bbase = (size_t)bb * NFULL * planeStride;

    float2 ring[7][5];
    float acc = 0.0f;

    for (int base = 0; base < nslices; base += 7) {
#pragma unroll
        for (int u = 0; u < 7; ++u) {
            const int ss = base + u;            // uniform across block
            if (ss < nslices) {
                const int dIn = d0 + ss;
                const float* Xp = X + bbase + (size_t)dIn * planeStride;
                const float* Yp = Y + bbase + (size_t)dIn * planeStride;

                // ---- Phase A: 7-tap sums along W for 5 products ----
                {
                    int gr = h0 + rA0; if (gr > NFULL - 1) gr = NFULL - 1;
                    const int coff = w0 + 2 * sA;
                    phaseA_task(Xp + gr * NFULL + coff, Yp + gr * NFULL + coff,
                                s1 + rA0 * 36 + 2 * sA);
                    if (tid < 96) {
                        int gr2 = h0 + rA1; if (gr2 > NFULL - 1) gr2 = NFULL - 1;
                        phaseA_task(Xp + gr2 * NFULL + coff, Yp + gr2 * NFULL + coff,
                                    s1 + rA1 * 36 + 2 * sA);
                    }
                }
                __syncthreads();

                // ---- Phase B: rolling 7-row sums along H ----
                if (tid < 80) {
                    const float* src = s1 + qB * 792 + 2 * sB;
                    float*       dst = s2 + qB * 584 + 2 * sB;
                    float2 win[7];
                    float ax = 0.f, ay = 0.f;
#pragma unroll
                    for (int r = 0; r < 22; ++r) {
                        float2 v = *(const float2*)(src + r * 36);
                        ax += v.x; ay += v.y;
                        if (r >= 7) { ax -= win[r % 7].x; ay -= win[r % 7].y; }
                        win[r % 7] = v;
                        if (r >= 6) *(float2*)(dst + (r - 6) * 36) = make_float2(ax, ay);
                    }
                }
                __syncthreads();

                // ---- Phase C: ring over D + SSIM ----
#pragma unroll
                for (int q = 0; q < 5; ++q)
                    ring[u][q] = *(const float2*)(s2 + q * 584 + hC * 36 + 2 * sC);

                if (ss >= 6) {
                    float R[5][2];
#pragma unroll
                    for (int q = 0; q < 5; ++q) {
                        float a = 0.f, b = 0.f;
#pragma unroll
                        for (int k = 0; k < 7; ++k) { a += ring[k][q].x; b += ring[k][q].y; }
                        R[q][0] = a; R[q][1] = b;
                    }
#pragma unroll
                    for (int j = 0; j < 2; ++j) {
                        const bool vld = j ? vld1 : vld0;
                        if (vld) {
                            float ux  = R[0][j] * inv_n, uy  = R[1][j] * inv_n;
                            float uxx = R[2][j] * inv_n, uyy = R[3][j] * inv_n;
                            float uxy = R[4][j] * inv_n;
                            float vx  = covn * (uxx - ux * ux);
                            float vy  = covn * (uyy - uy * uy);
                            float vxy = covn * (uxy - ux * uy);
                            float A1  = 2.f * ux * uy + c1;
                            float A2  = 2.f * vxy + c2;
                            float B1v = ux * ux + uy * uy + c1;
                            float B2v = vx + vy + c2;
                            acc += (A1 * A2) / (B1v * B2v);
                        }
                    }
                }
            }
        }
    }

    // ---- reduction: wave shuffle -> LDS -> double atomic ----
#pragma unroll
    for (int off = 32; off; off >>= 1) acc += __shfl_down(acc, off);
    __syncthreads();
    if ((tid & 63) == 0) s1[tid >> 6] = acc;
    __syncthreads();
    if (tid == 0) {
        double t = (double)s1[0] + (double)s1[1] + (double)s1[2] + (double)s1[3];
        atomicAdd(ws, t);
    }
}

__global__ void ssim3d_finalize(const double* __restrict__ ws, float* __restrict__ out)
{
    out[0] = (float)(ws[0] * (1.0 / 7263392.0)); // 4 * 122^3
}

extern "C" void kernel_launch(void* const* d_in, const int* in_sizes, int n_in,
                              void* d_out, int out_size, void* d_ws, size_t ws_size,
                              hipStream_t stream)
{
    const float* X  = (const float*)d_in[0];
    const float* Y  = (const float*)d_in[1];
    const float* DR = (const float*)d_in[2];
    double* ws = (double*)d_ws;

    hipMemsetAsync(d_ws, 0, sizeof(double), stream);
    ssim3d_kernel<<<512, 256, 0, stream>>>(X, Y, DR, ws);
    ssim3d_finalize<<<1, 1, 0, stream>>>(ws, (float*)d_out);
}